// Round 8
// baseline (1136.932 us; speedup 1.0000x reference)
//
#include <hip/hip_runtime.h>
#include <cmath>

#define D_K 768
#define GK 640
#define KC_N 24           // 768/32 k-chunks
#define HALF_TILE 10240   // halves: 20 nc * 64 lanes * 8
#define TILE_HALVES 20480 // hi+lo tile per (kc, group) = 40960 B

typedef _Float16 f16x8 __attribute__((ext_vector_type(8)));
typedef float f32x4 __attribute__((ext_vector_type(4)));

typedef __attribute__((address_space(1))) const void* as1cv;
typedef __attribute__((address_space(3))) void* as3v;

// ---------------- prep: zero bins+ticket + swizzle W (fp32 -> fp16 hi/lo, MFMA B-frag order) ----
__global__ __launch_bounds__(256) void prep_kernel(const float* __restrict__ W,
        unsigned* __restrict__ bins, _Float16* __restrict__ WB) {
    int t = blockIdx.x * 256 + threadIdx.x;   // 240*256 = 61440 = 960 frags * 64 lanes
    if (t < 1344) bins[t] = 0u;               // counts[640] + probsum[640] + ticket
    int fid = t >> 6;
    int l = t & 63;
    int kc = fid / 40, nc = fid - kc * 40;
    int g = nc / 20, ncl = nc - g * 20;
    int n = nc * 16 + (l & 15);
    int k0 = kc * 32 + (l >> 4) * 8;
    f16x8 hi, lo;
#pragma unroll
    for (int j = 0; j < 8; ++j) {
        float wv = W[(size_t)(k0 + j) * GK + n];
        _Float16 h = (_Float16)wv;
        hi[j] = h;
        lo[j] = (_Float16)(wv - (float)h);
    }
    size_t base = (size_t)(kc * 2 + g) * TILE_HALVES + ncl * 512 + l * 8;
    *(f16x8*)(WB + base) = hi;
    *(f16x8*)(WB + base + HALF_TILE) = lo;
}

// ---------------- main (ABLATION TEMPLATE, hardened) ----------------
// V=0 FULL (R3 body: 64 rows x 320 cols, 8 waves, single 40KB tile, 2 barriers/kc, fused fin)
// V=1 NOEPI   : K-loop+bias only, acc kept alive, early return  -> isolates epilogue cost
// V=2 NOSTAGE : no global_load_lds (barriers kept)              -> isolates B-stage cost
// V=3 NOCONV  : A-convert replaced by free bitcast              -> isolates convert VALU cost
// Fused finalize runs ONLY in V0 (dummy variants never touch ticket logic).
template<int V>
__global__ __launch_bounds__(512, 4) void main_kernel(
        const float* __restrict__ x, const float* __restrict__ bias,
        const float* __restrict__ noise, const float* __restrict__ cb,
        const _Float16* __restrict__ WB,
        float* __restrict__ out, unsigned* __restrict__ counts, float* __restrict__ probsum,
        unsigned* __restrict__ ticket, float* __restrict__ out2)
{
    __shared__ __align__(16) char smem[40960];            // single-buffer B tile
    float (*s_pmax)[64]  = (float(*)[64])(smem);          // epilogue overlays (post-K-loop)
    int   (*s_pcol)[64]  = (int(*)[64])(smem + 1024);
    float (*s_pgmax)[64] = (float(*)[64])(smem + 2048);
    int   (*s_pgcol)[64] = (int(*)[64])(smem + 3072);
    float (*s_psum)[64]  = (float(*)[64])(smem + 4096);
    float* s_fmax  = (float*)(smem + 5120);
    float* s_fsum  = (float*)(smem + 5376);
    int*   s_fgcol = (int*)(smem + 5632);
    float* s_bins  = (float*)(smem + 5888);               // 1280 B (ends 7168)
    int*   s_last  = (int*)(smem + 7168);
    float* s_red   = (float*)(smem + 7184);

    int tid = threadIdx.x;
    int bx = blockIdx.x;
    int g  = (bx >> 3) & 1;
    int rb = (bx & 7) | ((bx >> 4) << 3);
    int r0 = rb * 64;
    int w = tid >> 6;
    int l = tid & 63;
    int lrow = l >> 4;
    int lcol = l & 15;
    int mch = w >> 2;
    int s = w & 3;
    int s5 = s * 5;

    f32x4 acc[2][5];
#pragma unroll
    for (int i = 0; i < 2; ++i)
#pragma unroll
        for (int j = 0; j < 5; ++j) acc[i][j] = (f32x4){0.f, 0.f, 0.f, 0.f};

    const float* xb0 = x + (size_t)(r0 + mch * 32 + lcol) * D_K + lrow * 8;
    const float* xb1 = xb0 + 16 * D_K;

    auto stage = [&](int kc) {
        if constexpr (V != 2) {
            const char* src = (const char*)(WB + (size_t)(kc * 2 + g) * TILE_HALVES);
            char* dst = smem;
#pragma unroll
            for (int kk = 0; kk < 5; ++kk) {
                int u = tid + kk * 512;
                __builtin_amdgcn_global_load_lds((as1cv)(src + (size_t)u * 16),
                                                 (as3v)(dst + u * 16), 16, 0, 0);
            }
        }
    };

    stage(0);
    f32x4 a00 = *(const f32x4*)xb0, a01 = *(const f32x4*)(xb0 + 4);
    f32x4 a10 = *(const f32x4*)xb1, a11 = *(const f32x4*)(xb1 + 4);

    for (int kc = 0; kc < KC_N; ++kc) {
        // 1) convert current A (VALU) — or free bitcast for V3
        f16x8 ah[2], al[2];
        if constexpr (V != 3) {
#pragma unroll
            for (int j = 0; j < 4; ++j) {
                float f;
                _Float16 h;
                f = a00[j]; h = (_Float16)f; ah[0][j] = h;     al[0][j] = (_Float16)(f - (float)h);
                f = a01[j]; h = (_Float16)f; ah[0][4 + j] = h; al[0][4 + j] = (_Float16)(f - (float)h);
                f = a10[j]; h = (_Float16)f; ah[1][j] = h;     al[1][j] = (_Float16)(f - (float)h);
                f = a11[j]; h = (_Float16)f; ah[1][4 + j] = h; al[1][4 + j] = (_Float16)(f - (float)h);
            }
        } else {
            ah[0] = __builtin_bit_cast(f16x8, a00); al[0] = __builtin_bit_cast(f16x8, a01);
            ah[1] = __builtin_bit_cast(f16x8, a10); al[1] = __builtin_bit_cast(f16x8, a11);
        }
        __syncthreads();    // B tile kc visible; prior readers done

        // 2) A prefetch for next kc
        int kn = (kc < KC_N - 1) ? kc + 1 : 0;
        f32x4 n00 = *(const f32x4*)(xb0 + kn * 32), n01 = *(const f32x4*)(xb0 + kn * 32 + 4);
        f32x4 n10 = *(const f32x4*)(xb1 + kn * 32), n11 = *(const f32x4*)(xb1 + kn * 32 + 4);

        // 3) MFMA: 3-product fp16x2 (hh + lh + hl)
        const _Float16* sB = (const _Float16*)smem;
#pragma unroll
        for (int j = 0; j < 5; ++j) {
            int ncl = s5 + j;
            f16x8 bh = *(const f16x8*)(sB + ncl * 512 + l * 8);
            f16x8 bl = *(const f16x8*)(sB + HALF_TILE + ncl * 512 + l * 8);
            acc[0][j] = __builtin_amdgcn_mfma_f32_16x16x32_f16(ah[0], bh, acc[0][j], 0, 0, 0);
            acc[0][j] = __builtin_amdgcn_mfma_f32_16x16x32_f16(al[0], bh, acc[0][j], 0, 0, 0);
            acc[0][j] = __builtin_amdgcn_mfma_f32_16x16x32_f16(ah[0], bl, acc[0][j], 0, 0, 0);
            acc[1][j] = __builtin_amdgcn_mfma_f32_16x16x32_f16(ah[1], bh, acc[1][j], 0, 0, 0);
            acc[1][j] = __builtin_amdgcn_mfma_f32_16x16x32_f16(al[1], bh, acc[1][j], 0, 0, 0);
            acc[1][j] = __builtin_amdgcn_mfma_f32_16x16x32_f16(ah[1], bl, acc[1][j], 0, 0, 0);
        }
        __syncthreads();    // all waves finished reading tile kc (epilogue overlay safe)
        if (kc < KC_N - 1) stage(kc + 1);
        a00 = n00; a01 = n01; a10 = n10; a11 = n11;
    }

    // bias
#pragma unroll
    for (int j = 0; j < 5; ++j) {
        float bb = bias[g * 320 + (s5 + j) * 16 + lcol];
#pragma unroll
        for (int i = 0; i < 2; ++i)
#pragma unroll
            for (int r = 0; r < 4; ++r) acc[i][j][r] += bb;
    }

    if constexpr (V == 1) {   // NOEPI: keep acc live (anti-DCE, rule #17), skip epilogue
#pragma unroll
        for (int i = 0; i < 2; ++i)
#pragma unroll
            for (int j = 0; j < 5; ++j)
                asm volatile("" :: "v"(acc[i][j][0]), "v"(acc[i][j][1]),
                                   "v"(acc[i][j][2]), "v"(acc[i][j][3]));
        return;
    }

    // ---------------- epilogue ----------------
#pragma unroll
    for (int i = 0; i < 2; ++i) {
#pragma unroll
        for (int r = 0; r < 4; ++r) {
            int row = mch * 32 + i * 16 + lrow * 4 + r;
            float vmax = -3.4e38f; int vcol = 0;
            float gmax = -3.4e38f; int gcol = 0;
            const float* np = noise + (size_t)(r0 + row) * GK + g * 320 + s5 * 16 + lcol;
#pragma unroll
            for (int j = 0; j < 5; ++j) {
                float v = acc[i][j][r];
                int c = (s5 + j) * 16 + lcol;
                if (v > vmax) { vmax = v; vcol = c; }
                float u = np[j * 16] * (1.0f - 2e-6f) + 1e-6f;
                float gn = -__logf(-__logf(u));
                float z = v + gn;
                if (z > gmax) { gmax = z; gcol = c; }
            }
#pragma unroll
            for (int off = 1; off < 16; off <<= 1) {
                float ov = __shfl_xor(vmax, off); int oc = __shfl_xor(vcol, off);
                if (ov > vmax || (ov == vmax && oc < vcol)) { vmax = ov; vcol = oc; }
                float og = __shfl_xor(gmax, off); int ogc = __shfl_xor(gcol, off);
                if (og > gmax || (og == gmax && ogc < gcol)) { gmax = og; gcol = ogc; }
            }
            if (lcol == 0) {
                s_pmax[s][row] = vmax; s_pcol[s][row] = vcol;
                s_pgmax[s][row] = gmax; s_pgcol[s][row] = gcol;
            }
        }
    }
    if (tid < 320) s_bins[tid] = 0.0f;
    __syncthreads();

    if (tid < 64) {
        int row = tid;
        float vmax = -3.4e38f; int vcol = 0;
        float gmax = -3.4e38f; int gcol = 0;
        for (int ss = 0; ss < 4; ++ss) {
            float v = s_pmax[ss][row];
            if (v > vmax) { vmax = v; vcol = s_pcol[ss][row]; }
            float z = s_pgmax[ss][row];
            if (z > gmax) { gmax = z; gcol = s_pgcol[ss][row]; }
        }
        s_fmax[row] = vmax;
        s_fgcol[row] = gcol;
        atomicAdd(&counts[g * 320 + vcol], 1u);
    }
    __syncthreads();

#pragma unroll
    for (int i = 0; i < 2; ++i) {
#pragma unroll
        for (int r = 0; r < 4; ++r) {
            int row = mch * 32 + i * 16 + lrow * 4 + r;
            float M = s_fmax[row];
            float sm = 0.f;
#pragma unroll
            for (int j = 0; j < 5; ++j) sm += __expf(acc[i][j][r] - M);
#pragma unroll
            for (int off = 1; off < 16; off <<= 1) sm += __shfl_xor(sm, off);
            if (lcol == 0) s_psum[s][row] = sm;
        }
    }
    __syncthreads();
    if (tid < 64) {
        float S = 0.f;
        for (int ss = 0; ss < 4; ++ss) S += s_psum[ss][tid];
        s_fsum[tid] = S;
    }
    __syncthreads();

    {
        float part[5] = {0.f, 0.f, 0.f, 0.f, 0.f};
#pragma unroll
        for (int i = 0; i < 2; ++i) {
#pragma unroll
            for (int r = 0; r < 4; ++r) {
                int row = mch * 32 + i * 16 + lrow * 4 + r;
                float M = s_fmax[row];
                float invS = 1.0f / s_fsum[row];
#pragma unroll
                for (int j = 0; j < 5; ++j)
                    part[j] += __expf(acc[i][j][r] - M) * invS;
            }
        }
#pragma unroll
        for (int j = 0; j < 5; ++j) {
            float p = part[j];
            p += __shfl_xor(p, 16);
            p += __shfl_xor(p, 32);
            if (lrow == 0) atomicAdd(&s_bins[(s5 + j) * 16 + lcol], p);
        }
    }
    __syncthreads();
    if (tid < 320) atomicAdd(&probsum[g * 320 + tid], s_bins[tid]);

    {
        int row = tid >> 3, jj = tid & 7;
        int wcol = g * 320 + s_fgcol[row];
        const f32x4* src = (const f32x4*)(cb + (size_t)wcol * 128);
        f32x4* dst = (f32x4*)(out + (size_t)(r0 + row) * 256 + g * 128);
#pragma unroll
        for (int k = 0; k < 4; ++k) dst[k * 8 + jj] = src[k * 8 + jj];
    }

    // fused finalize — V0 ONLY
    if constexpr (V == 0) {
        __syncthreads();
        if (tid == 0) {
            __threadfence();
            unsigned prev = atomicAdd(ticket, 1u);
            *s_last = (prev == 1023u) ? 1 : 0;
        }
        __syncthreads();
        if (*s_last) {
            __threadfence();
            if (w < 4) {
                float v = 0.f;
#pragma unroll
                for (int k = 0; k < 5; ++k) {
                    int idx = (w & 1) * 320 + l + 64 * k;
                    float p;
                    if (w < 2)
                        p = (float)__hip_atomic_load(&counts[idx], __ATOMIC_RELAXED,
                                                     __HIP_MEMORY_SCOPE_AGENT) * (1.0f / 32768.0f);
                    else
                        p = __hip_atomic_load(&probsum[idx], __ATOMIC_RELAXED,
                                              __HIP_MEMORY_SCOPE_AGENT) * (1.0f / 32768.0f);
                    v += p * logf(p + 1e-7f);
                }
#pragma unroll
                for (int off = 1; off < 64; off <<= 1) v += __shfl_xor(v, off);
                if (l == 0) s_red[w] = v;
            }
            __syncthreads();
            if (tid < 2) out2[tid] = expf(-s_red[tid * 2]) + expf(-s_red[tid * 2 + 1]);
        }
    }
}

extern "C" void kernel_launch(void* const* d_in, const int* in_sizes, int n_in,
                              void* d_out, int out_size, void* d_ws, size_t ws_size,
                              hipStream_t stream) {
    const float* x     = (const float*)d_in[0];   // [16,2048,768]
    const float* W     = (const float*)d_in[1];   // [768,640]
    const float* b     = (const float*)d_in[2];   // [640]
    const float* cb    = (const float*)d_in[3];   // [1,640,128]
    const float* noise = (const float*)d_in[4];   // [32768,2,320]
    float* out = (float*)d_out;

    char* ws = (char*)d_ws;
    unsigned* counts = (unsigned*)ws;             // [640] u32
    float* probsum   = (float*)(ws + 2560);       // [640] f32
    unsigned* ticket = (unsigned*)(ws + 5120);    // [1] u32 (zeroed by prep)
    _Float16* WB     = (_Float16*)(ws + 8192);    // 1,966,080 B

    // dummy sinks for ablation variants (garbage-tolerant; never read by the test)
    unsigned* counts_d = (unsigned*)(ws + 2097152);
    float*    probsum_d= (float*)(ws + 2097152 + 2560);
    unsigned* ticket_d = (unsigned*)(ws + 2097152 + 5120);
    float*    out_d    = (float*)(ws + 4194304);  // 32 MB + scalars

    hipLaunchKernelGGL(prep_kernel, dim3(240), dim3(256), 0, stream, W, counts, WB);
    hipLaunchKernelGGL((main_kernel<0>), dim3(1024), dim3(512), 0, stream,
                       x, b, noise, cb, WB, out, counts, probsum, ticket, out + 8388608);
    hipLaunchKernelGGL((main_kernel<1>), dim3(1024), dim3(512), 0, stream,
                       x, b, noise, cb, WB, out_d, counts_d, probsum_d, ticket_d, out_d + 8388608);
    hipLaunchKernelGGL((main_kernel<2>), dim3(1024), dim3(512), 0, stream,
                       x, b, noise, cb, WB, out_d, counts_d, probsum_d, ticket_d, out_d + 8388608);
    hipLaunchKernelGGL((main_kernel<3>), dim3(1024), dim3(512), 0, stream,
                       x, b, noise, cb, WB, out_d, counts_d, probsum_d, ticket_d, out_d + 8388608);
}